// Round 9
// baseline (266.785 us; speedup 1.0000x reference)
//
#include <hip/hip_runtime.h>
#include <hip/hip_fp16.h>

#define N_NODES 100000
#define N_EDGES 3200000
#define F_IN 128
#define HID 16

#define SHIFT 7
#define NPB 128                                 // nodes per bucket
#define NB 782                                  // ceil(N/128)
#define CHUNK 3072
#define NCHUNK ((N_EDGES + CHUNK - 1) / CHUNK)  // 1042
#define MAXPER 12                               // CHUNK/256 edges cached per thread
#define HALF 4608                               // region cap per bucket (mean 4096, +8 sigma)
#define SMAX 18                                 // HALF/256 rounded up
#define CPAD 16

__device__ __forceinline__ float2 h2f(unsigned u) {
    __half2 h;
    *reinterpret_cast<unsigned*>(&h) = u;
    return __half22float2(h);
}
__device__ __forceinline__ unsigned f2h(float a, float b) {
    __half2 h = __floats2half2_rn(a, b);
    return *reinterpret_cast<unsigned*>(&h);
}

// ---------------- partition into 782 fixed bucket regions, reg-cached, LDS-staged writes ----------------
__global__ __launch_bounds__(256) void k_part(const int* __restrict__ src,
                                              const int* __restrict__ dst,
                                              int* __restrict__ cursor,
                                              unsigned* __restrict__ ebuf, int E) {
    __shared__ int lcnt[1024];
    __shared__ int sc[1024];
    __shared__ int lcur[1024];
    __shared__ int dlt[1024];
    __shared__ unsigned sbuf[CHUNK];         // 12 KB
    __shared__ unsigned short sbkt[CHUNK];   // 6 KB
    int t = threadIdx.x;
#pragma unroll
    for (int q = 0; q < 4; q++) lcnt[t + 256 * q] = 0;
    __syncthreads();
    int e0 = blockIdx.x * CHUNK;
    int ne = min(CHUNK, E - e0);
    int es[MAXPER], eb[MAXPER];
    int nq = 0;
    for (int e = t; e < ne; e += 256) {
        es[nq] = src[e0 + e];
        eb[nq] = dst[e0 + e];
        nq++;
    }
    for (int q = 0; q < nq; q++) atomicAdd(&lcnt[eb[q] >> SHIFT], 1);
    __syncthreads();
    // scan 1024 entries: 4 segments of 256 in lockstep, then splice
#pragma unroll
    for (int q = 0; q < 4; q++) sc[t + 256 * q] = lcnt[t + 256 * q];
    __syncthreads();
#pragma unroll
    for (int o = 1; o < 256; o <<= 1) {
        int a0 = (t >= o) ? sc[t - o] : 0;
        int a1 = (t >= o) ? sc[256 + t - o] : 0;
        int a2 = (t >= o) ? sc[512 + t - o] : 0;
        int a3 = (t >= o) ? sc[768 + t - o] : 0;
        __syncthreads();
        sc[t] += a0;
        sc[256 + t] += a1;
        sc[512 + t] += a2;
        sc[768 + t] += a3;
        __syncthreads();
    }
    int tot0 = sc[255], tot1 = sc[511], tot2 = sc[767];
    __syncthreads();
    sc[256 + t] += tot0;
    sc[512 + t] += tot0 + tot1;
    sc[768 + t] += tot0 + tot1 + tot2;
    __syncthreads();
#pragma unroll
    for (int q = 0; q < 4; q++) {
        int b = t + 256 * q;
        int c = lcnt[b];
        int o = sc[b] - c;
        lcur[b] = o;
        if (b < NB && c) dlt[b] = b * HALF + atomicAdd(&cursor[b * CPAD], c) - o;
    }
    __syncthreads();
    for (int q = 0; q < nq; q++) {
        int b = eb[q] >> SHIFT;
        int p = atomicAdd(&lcur[b], 1);
        sbuf[p] = ((unsigned)es[q] << SHIFT) | (unsigned)(eb[q] & (NPB - 1));
        sbkt[p] = (unsigned short)b;
    }
    __syncthreads();
    for (int k = t; k < ne; k += 256) ebuf[k + dlt[sbkt[k]]] = sbuf[k];
}

// ---------------- per-bucket counting-sort (reg-cached, single read) + fused GEMM1 (fp16 out) ----------------
__global__ __launch_bounds__(256) void k_sort2(const unsigned* __restrict__ ebuf,
                                               const int* __restrict__ cursor,
                                               const float* __restrict__ x,
                                               const float* __restrict__ W1,
                                               int* __restrict__ ebuf2,
                                               int2* __restrict__ offse,
                                               float* __restrict__ dinv,
                                               uint4* __restrict__ gt, int N) {
    __shared__ int hist[NPB];
    __shared__ int sc2[NPB];
    __shared__ int cur[NPB];
    __shared__ int dg[NPB];
    __shared__ int sbufS[HALF];       // 18 KB
    __shared__ float w1s[F_IN * HID]; // 8 KB
    int t = threadIdx.x;
    int b = blockIdx.x;
    for (int idx = t; idx < F_IN * HID; idx += 256) w1s[idx] = W1[idx];
    if (t < NPB) hist[t] = 0;
    __syncthreads();
    int cnt = min(cursor[b * CPAD], HALF);
    int base = b * HALF;
    unsigned eu[SMAX];
    int nq = 0;
    for (int e = t; e < cnt; e += 256) eu[nq++] = ebuf[base + e];
    for (int q = 0; q < nq; q++) atomicAdd(&hist[eu[q] & (NPB - 1u)], 1);
    __syncthreads();
    int v = (t < NPB) ? hist[t] : 0;
    if (t < NPB) sc2[t] = v;
    __syncthreads();
    for (int o = 1; o < NPB; o <<= 1) {
        int xv = (t < NPB && t >= o) ? sc2[t - o] : 0;
        __syncthreads();
        if (t < NPB) sc2[t] += xv;
        __syncthreads();
    }
    if (t < NPB) {
        int ex = sc2[t] - v;
        cur[t] = ex;
        dg[t] = v;
        int i = b * NPB + t;
        if (i < N) {
            offse[i] = make_int2(base + ex, base + ex + v);
            dinv[i] = rsqrtf((float)(v + 1));  // +1 self-loop
        }
    }
    __syncthreads();
    for (int q = 0; q < nq; q++) {
        int p = atomicAdd(&cur[eu[q] & (NPB - 1u)], 1);
        sbufS[p] = (int)(eu[q] >> SHIFT);
    }
    __syncthreads();
    for (int k = t; k < cnt; k += 256) ebuf2[base + k] = sbufS[k];  // coalesced
    // ---- fused GEMM1: g = (x @ W1) * dinv, fp16 storage (2 lanes/row, 128 nodes) ----
    int r = t >> 1, hf = t & 1;
    int i = b * NPB + r;
    float acc[HID];
#pragma unroll
    for (int n = 0; n < HID; n++) acc[n] = 0.f;
    if (i < N) {
        const float4* xr = (const float4*)(x + (size_t)i * F_IN + hf * (F_IN / 2));
#pragma unroll 4
        for (int k4 = 0; k4 < F_IN / 8; k4++) {
            float4 xv = xr[k4];
            int k = hf * (F_IN / 2) + k4 * 4;
#pragma unroll
            for (int n = 0; n < HID; n++) {
                acc[n] += xv.x * w1s[(k + 0) * HID + n] + xv.y * w1s[(k + 1) * HID + n] +
                          xv.z * w1s[(k + 2) * HID + n] + xv.w * w1s[(k + 3) * HID + n];
            }
        }
    }
#pragma unroll
    for (int n = 0; n < HID; n++) acc[n] += __shfl_xor(acc[n], 1);
    if (hf == 0 && i < N) {
        float dv = rsqrtf((float)(dg[r] + 1));
        uint4 w0, w1;
        w0.x = f2h(acc[0] * dv, acc[1] * dv);
        w0.y = f2h(acc[2] * dv, acc[3] * dv);
        w0.z = f2h(acc[4] * dv, acc[5] * dv);
        w0.w = f2h(acc[6] * dv, acc[7] * dv);
        w1.x = f2h(acc[8] * dv, acc[9] * dv);
        w1.y = f2h(acc[10] * dv, acc[11] * dv);
        w1.z = f2h(acc[12] * dv, acc[13] * dv);
        w1.w = f2h(acc[14] * dv, acc[15] * dv);
        gt[2 * (size_t)i] = w0;
        gt[2 * (size_t)i + 1] = w1;
    }
}

// ---------------- gather conv1 (fp16 table): h1 = relu(dinv*(sum+self)+b1), fp16 out ----------------
__global__ __launch_bounds__(256) void k_gather1(const uint4* __restrict__ gt,
                                                 const int2* __restrict__ offse,
                                                 const int* __restrict__ ebuf2,
                                                 const float* __restrict__ dinv,
                                                 const float* __restrict__ b1,
                                                 uint4* __restrict__ ht, int N) {
    int i = (blockIdx.x * 256 + threadIdx.x) >> 6;
    int lane = threadIdx.x & 63;
    if (i >= N) return;
    int2 oe = offse[i];
    int j = lane & 1;
    float2 a0 = make_float2(0.f, 0.f), a1 = a0, a2 = a0, a3 = a0;
    for (int e = oe.x + (lane >> 1); e < oe.y; e += 32) {
        int s = ebuf2[e];
        uint4 v = gt[2 * (size_t)s + j];
        float2 f;
        f = h2f(v.x); a0.x += f.x; a0.y += f.y;
        f = h2f(v.y); a1.x += f.x; a1.y += f.y;
        f = h2f(v.z); a2.x += f.x; a2.y += f.y;
        f = h2f(v.w); a3.x += f.x; a3.y += f.y;
    }
#pragma unroll
    for (int mk = 2; mk <= 32; mk <<= 1) {
        a0.x += __shfl_xor(a0.x, mk); a0.y += __shfl_xor(a0.y, mk);
        a1.x += __shfl_xor(a1.x, mk); a1.y += __shfl_xor(a1.y, mk);
        a2.x += __shfl_xor(a2.x, mk); a2.y += __shfl_xor(a2.y, mk);
        a3.x += __shfl_xor(a3.x, mk); a3.y += __shfl_xor(a3.y, mk);
    }
    if (lane < 2) {
        uint4 sv = gt[2 * (size_t)i + j];
        float2 f;
        f = h2f(sv.x); a0.x += f.x; a0.y += f.y;
        f = h2f(sv.y); a1.x += f.x; a1.y += f.y;
        f = h2f(sv.z); a2.x += f.x; a2.y += f.y;
        f = h2f(sv.w); a3.x += f.x; a3.y += f.y;
        float dv = dinv[i];
        float4 bb0 = ((const float4*)b1)[2 * j];
        float4 bb1 = ((const float4*)b1)[2 * j + 1];
        float o0 = fmaxf(dv * a0.x + bb0.x, 0.f), o1 = fmaxf(dv * a0.y + bb0.y, 0.f);
        float o2 = fmaxf(dv * a1.x + bb0.z, 0.f), o3 = fmaxf(dv * a1.y + bb0.w, 0.f);
        float o4 = fmaxf(dv * a2.x + bb1.x, 0.f), o5 = fmaxf(dv * a2.y + bb1.y, 0.f);
        float o6 = fmaxf(dv * a3.x + bb1.z, 0.f), o7 = fmaxf(dv * a3.y + bb1.w, 0.f);
        uint4 w;
        w.x = f2h(o0, o1);
        w.y = f2h(o2, o3);
        w.z = f2h(o4, o5);
        w.w = f2h(o6, o7);
        ht[2 * (size_t)i + j] = w;
    }
}

// ---------------- GEMM2: g2 = (h1 @ W2) * dinv, fp16 in/out ----------------
__global__ __launch_bounds__(256) void k_gemm2(const uint4* __restrict__ ht,
                                               const float* __restrict__ W2,
                                               const float* __restrict__ dinv,
                                               uint4* __restrict__ g2t, int N) {
    __shared__ float w[HID * HID];
    w[threadIdx.x] = W2[threadIdx.x];
    __syncthreads();
    int i = blockIdx.x * 256 + threadIdx.x;
    if (i >= N) return;
    uint4 r0 = ht[2 * (size_t)i], r1 = ht[2 * (size_t)i + 1];
    float hv[HID];
    float2 f;
    f = h2f(r0.x); hv[0] = f.x; hv[1] = f.y;
    f = h2f(r0.y); hv[2] = f.x; hv[3] = f.y;
    f = h2f(r0.z); hv[4] = f.x; hv[5] = f.y;
    f = h2f(r0.w); hv[6] = f.x; hv[7] = f.y;
    f = h2f(r1.x); hv[8] = f.x; hv[9] = f.y;
    f = h2f(r1.y); hv[10] = f.x; hv[11] = f.y;
    f = h2f(r1.z); hv[12] = f.x; hv[13] = f.y;
    f = h2f(r1.w); hv[14] = f.x; hv[15] = f.y;
    float dv = dinv[i];
    float out[HID];
#pragma unroll
    for (int n = 0; n < HID; n++) out[n] = 0.f;
#pragma unroll
    for (int k = 0; k < HID; k++) {
#pragma unroll
        for (int n = 0; n < HID; n++) out[n] += hv[k] * w[k * HID + n];
    }
    uint4 w0, w1;
    w0.x = f2h(out[0] * dv, out[1] * dv);
    w0.y = f2h(out[2] * dv, out[3] * dv);
    w0.z = f2h(out[4] * dv, out[5] * dv);
    w0.w = f2h(out[6] * dv, out[7] * dv);
    w1.x = f2h(out[8] * dv, out[9] * dv);
    w1.y = f2h(out[10] * dv, out[11] * dv);
    w1.z = f2h(out[12] * dv, out[13] * dv);
    w1.w = f2h(out[14] * dv, out[15] * dv);
    g2t[2 * (size_t)i] = w0;
    g2t[2 * (size_t)i + 1] = w1;
}

// ---------------- gather conv2 (fp16 table) + fused node-dot -> nd ----------------
__global__ __launch_bounds__(256) void k_gather2(const uint4* __restrict__ g2t,
                                                 const int2* __restrict__ offse,
                                                 const int* __restrict__ ebuf2,
                                                 const float* __restrict__ dinv,
                                                 const float* __restrict__ b2,
                                                 const float* __restrict__ Wf,
                                                 const float* __restrict__ bf,
                                                 float2* __restrict__ nd, int N) {
    __shared__ float wfs[33];
    if (threadIdx.x < 33) wfs[threadIdx.x] = (threadIdx.x < 32) ? Wf[threadIdx.x] : bf[0];
    __syncthreads();
    int i = (blockIdx.x * 256 + threadIdx.x) >> 6;
    int lane = threadIdx.x & 63;
    if (i >= N) return;
    int2 oe = offse[i];
    int j = lane & 1;
    float2 a0 = make_float2(0.f, 0.f), a1 = a0, a2 = a0, a3 = a0;
    for (int e = oe.x + (lane >> 1); e < oe.y; e += 32) {
        int s = ebuf2[e];
        uint4 v = g2t[2 * (size_t)s + j];
        float2 f;
        f = h2f(v.x); a0.x += f.x; a0.y += f.y;
        f = h2f(v.y); a1.x += f.x; a1.y += f.y;
        f = h2f(v.z); a2.x += f.x; a2.y += f.y;
        f = h2f(v.w); a3.x += f.x; a3.y += f.y;
    }
#pragma unroll
    for (int mk = 2; mk <= 32; mk <<= 1) {
        a0.x += __shfl_xor(a0.x, mk); a0.y += __shfl_xor(a0.y, mk);
        a1.x += __shfl_xor(a1.x, mk); a1.y += __shfl_xor(a1.y, mk);
        a2.x += __shfl_xor(a2.x, mk); a2.y += __shfl_xor(a2.y, mk);
        a3.x += __shfl_xor(a3.x, mk); a3.y += __shfl_xor(a3.y, mk);
    }
    if (lane < 2) {
        uint4 sv = g2t[2 * (size_t)i + j];
        float2 f;
        f = h2f(sv.x); a0.x += f.x; a0.y += f.y;
        f = h2f(sv.y); a1.x += f.x; a1.y += f.y;
        f = h2f(sv.z); a2.x += f.x; a2.y += f.y;
        f = h2f(sv.w); a3.x += f.x; a3.y += f.y;
        float dv = dinv[i];
        float4 bb0 = ((const float4*)b2)[2 * j];
        float4 bb1 = ((const float4*)b2)[2 * j + 1];
        float o0 = dv * a0.x + bb0.x, o1 = dv * a0.y + bb0.y;
        float o2 = dv * a1.x + bb0.z, o3 = dv * a1.y + bb0.w;
        float o4 = dv * a2.x + bb1.x, o5 = dv * a2.y + bb1.y;
        float o6 = dv * a3.x + bb1.z, o7 = dv * a3.y + bb1.w;
        int k0 = 8 * j;
        float ps = o0 * wfs[k0 + 0] + o1 * wfs[k0 + 1] + o2 * wfs[k0 + 2] + o3 * wfs[k0 + 3] +
                   o4 * wfs[k0 + 4] + o5 * wfs[k0 + 5] + o6 * wfs[k0 + 6] + o7 * wfs[k0 + 7];
        float pd = o0 * wfs[16 + k0 + 0] + o1 * wfs[16 + k0 + 1] + o2 * wfs[16 + k0 + 2] +
                   o3 * wfs[16 + k0 + 3] + o4 * wfs[16 + k0 + 4] + o5 * wfs[16 + k0 + 5] +
                   o6 * wfs[16 + k0 + 6] + o7 * wfs[16 + k0 + 7];
        ps += __shfl_xor(ps, 1);
        pd += __shfl_xor(pd, 1);
        if (lane == 0) nd[i] = make_float2(ps, pd + wfs[32]);
    }
}

// ---------------- edge scoring: 8 B random reads from L2-resident nd ----------------
__global__ __launch_bounds__(256) void k_edge2(const int* __restrict__ src,
                                               const int* __restrict__ dst,
                                               const float2* __restrict__ nd,
                                               float* __restrict__ pred, int E) {
    int e = blockIdx.x * 256 + threadIdx.x;
    if (e >= E) return;
    pred[e] = nd[src[e]].x + nd[dst[e]].y;
}

extern "C" void kernel_launch(void* const* d_in, const int* in_sizes, int n_in,
                              void* d_out, int out_size, void* d_ws, size_t ws_size,
                              hipStream_t stream) {
    const float* x  = (const float*)d_in[0];
    const int*   ei = (const int*)d_in[1];
    const float* W1 = (const float*)d_in[2];
    const float* b1 = (const float*)d_in[3];
    const float* W2 = (const float*)d_in[4];
    const float* b2 = (const float*)d_in[5];
    const float* Wf = (const float*)d_in[6];
    const float* bf = (const float*)d_in[7];
    float* pred = (float*)d_out;

    const int N = N_NODES, E = N_EDGES;
    const int* src = ei;
    const int* dst = ei + E;

    // workspace layout (bytes); g2t aliases ebuf (dead after k_sort2). Total ~38 MB.
    char* w = (char*)d_ws;
    int*      cursor = (int*)(w + 0x0);           // 50 KB (stride CPAD)
    float*    dinv   = (float*)(w + 0x10000);     // 400 KB
    int2*     offse  = (int2*)(w + 0x80000);      // 800 KB
    float2*   nd     = (float2*)(w + 0x150000);   // 800 KB
    unsigned* ebuf   = (unsigned*)(w + 0x220000); // 782*4608*4 = 14.42 MB (dead after sort2)
    uint4*    g2t    = (uint4*)(w + 0x220000);    // 3.2 MB (aliases ebuf)
    int*      ebuf2  = (int*)(w + 0x1000000);     // 14.42 MB
    uint4*    gt     = (uint4*)(w + 0x1E00000);   // 3.2 MB (fp16 g table)
    uint4*    ht     = (uint4*)(w + 0x2140000);   // 3.2 MB (fp16 h1) -> end ~0x2450000

    const int B = 256;
    int gE   = (E + B - 1) / B;  // 12500
    int gN   = (N + B - 1) / B;  // 391
    int gN64 = (N * 64) / B;     // 25000 (wave per node)

    hipMemsetAsync(cursor, 0, NB * CPAD * sizeof(int), stream);
    k_part<<<NCHUNK, B, 0, stream>>>(src, dst, cursor, ebuf, E);
    k_sort2<<<NB, B, 0, stream>>>(ebuf, cursor, x, W1, ebuf2, offse, dinv, gt, N);
    k_gather1<<<gN64, B, 0, stream>>>(gt, offse, ebuf2, dinv, b1, ht, N);
    k_gemm2<<<gN, B, 0, stream>>>(ht, W2, dinv, g2t, N);
    k_gather2<<<gN64, B, 0, stream>>>(g2t, offse, ebuf2, dinv, b2, Wf, bf, nd, N);
    k_edge2<<<gE, B, 0, stream>>>(src, dst, nd, pred, E);
}

// Round 10
// 221.512 us; speedup vs baseline: 1.2044x; 1.2044x over previous
//
#include <hip/hip_runtime.h>
#include <hip/hip_fp16.h>

#define N_NODES 100000
#define N_EDGES 3200000
#define F_IN 128
#define HID 16

#define SHIFT 8
#define NPB 256                                 // nodes per bucket
#define NB 391                                  // ceil(N/256)
#define CHUNK 4096
#define NCHUNK ((N_EDGES + CHUNK - 1) / CHUNK)  // 782
#define MAXBE 9216                              // region cap per bucket (mean 8184, +11 sigma)
#define SMAX 36                                 // MAXBE/256
#define CPAD 16

__device__ __forceinline__ float2 h2f(unsigned u) {
    __half2 h;
    *reinterpret_cast<unsigned*>(&h) = u;
    return __half22float2(h);
}
__device__ __forceinline__ unsigned f2h(float a, float b) {
    __half2 h = __floats2half2_rn(a, b);
    return *reinterpret_cast<unsigned*>(&h);
}

// ---------------- partition into 391 fixed bucket regions, LDS-staged coalesced writes ----------------
__global__ __launch_bounds__(256) void k_part(const int* __restrict__ src,
                                              const int* __restrict__ dst,
                                              int* __restrict__ cursor,
                                              unsigned* __restrict__ ebuf, int E) {
    __shared__ int lcnt[512];
    __shared__ int sc[512];
    __shared__ int lcur[512];
    __shared__ int dlt[512];
    __shared__ unsigned sbuf[CHUNK];         // 16 KB
    __shared__ unsigned short sbkt[CHUNK];   // 8 KB
    int t = threadIdx.x;
    lcnt[t] = 0;
    lcnt[t + 256] = 0;
    __syncthreads();
    int e0 = blockIdx.x * CHUNK;
    int ne = min(CHUNK, E - e0);
    for (int e = t; e < ne; e += 256) atomicAdd(&lcnt[dst[e0 + e] >> SHIFT], 1);
    __syncthreads();
    sc[t] = lcnt[t];
    sc[t + 256] = lcnt[t + 256];
    __syncthreads();
#pragma unroll
    for (int o = 1; o < 256; o <<= 1) {
        int xv = (t >= o) ? sc[t - o] : 0;
        int yv = (t >= o) ? sc[256 + t - o] : 0;
        __syncthreads();
        sc[t] += xv;
        sc[256 + t] += yv;
        __syncthreads();
    }
    int tot1 = sc[255];
    __syncthreads();
    sc[256 + t] += tot1;
    __syncthreads();
    {
        int b1 = t, b2 = t + 256;
        int c1 = lcnt[b1], c2 = lcnt[b2];
        int o1 = sc[b1] - c1, o2 = sc[b2] - c2;
        lcur[b1] = o1;
        lcur[b2] = o2;
        if (b1 < NB && c1) dlt[b1] = b1 * MAXBE + atomicAdd(&cursor[b1 * CPAD], c1) - o1;
        if (b2 < NB && c2) dlt[b2] = b2 * MAXBE + atomicAdd(&cursor[b2 * CPAD], c2) - o2;
    }
    __syncthreads();
    for (int e = t; e < ne; e += 256) {
        int d = dst[e0 + e];
        int b = d >> SHIFT;
        int p = atomicAdd(&lcur[b], 1);
        sbuf[p] = ((unsigned)src[e0 + e] << SHIFT) | (unsigned)(d & (NPB - 1));
        sbkt[p] = (unsigned short)b;
    }
    __syncthreads();
    for (int k = t; k < ne; k += 256) ebuf[k + dlt[sbkt[k]]] = sbuf[k];
}

// ---------------- per-bucket counting-sort (single reg-cached read) + fused GEMM1 (fp16 out) ----------------
__global__ __launch_bounds__(256) void k_sort2(const unsigned* __restrict__ ebuf,
                                               const int* __restrict__ cursor,
                                               const float* __restrict__ x,
                                               const float* __restrict__ W1,
                                               int* __restrict__ ebuf2,
                                               int2* __restrict__ offse,
                                               float* __restrict__ dinv,
                                               uint4* __restrict__ gt, int N) {
    __shared__ int hist[NPB];
    __shared__ int sc2[NPB];
    __shared__ int cur[NPB];
    __shared__ int sbufS[MAXBE];      // 36 KB
    __shared__ float w1s[F_IN * HID]; // 8 KB
    int t = threadIdx.x;
    int b = blockIdx.x;
    for (int idx = t; idx < F_IN * HID; idx += 256) w1s[idx] = W1[idx];
    hist[t] = 0;
    __syncthreads();
    int cnt = min(cursor[b * CPAD], MAXBE);
    int base = b * MAXBE;
    unsigned eu[SMAX];
    int nq = 0;
    for (int e = t; e < cnt; e += 256) eu[nq++] = ebuf[base + e];
    for (int q = 0; q < nq; q++) atomicAdd(&hist[eu[q] & (NPB - 1u)], 1);
    __syncthreads();
    int v = hist[t];
    sc2[t] = v;
    __syncthreads();
#pragma unroll
    for (int o = 1; o < NPB; o <<= 1) {
        int xv = (t >= o) ? sc2[t - o] : 0;
        __syncthreads();
        sc2[t] += xv;
        __syncthreads();
    }
    int ex = sc2[t] - v;
    cur[t] = ex;
    int i = b * NPB + t;
    if (i < N) {
        offse[i] = make_int2(base + ex, base + ex + v);
        dinv[i] = rsqrtf((float)(v + 1));  // +1 self-loop
    }
    __syncthreads();
    for (int q = 0; q < nq; q++) {
        int p = atomicAdd(&cur[eu[q] & (NPB - 1u)], 1);
        sbufS[p] = (int)(eu[q] >> SHIFT);
    }
    __syncthreads();
    for (int k = t; k < cnt; k += 256) ebuf2[base + k] = sbufS[k];  // coalesced
    // ---- fused GEMM1: g = (x @ W1) * dinv, fp16 storage (1 thread/row, 256 nodes) ----
    if (i >= N) return;
    float acc[HID];
#pragma unroll
    for (int n = 0; n < HID; n++) acc[n] = 0.f;
    const float4* xr = (const float4*)(x + (size_t)i * F_IN);
#pragma unroll 4
    for (int k4 = 0; k4 < F_IN / 4; k4++) {
        float4 xv = xr[k4];
        int k = k4 * 4;
#pragma unroll
        for (int n = 0; n < HID; n++) {
            acc[n] += xv.x * w1s[(k + 0) * HID + n] + xv.y * w1s[(k + 1) * HID + n] +
                      xv.z * w1s[(k + 2) * HID + n] + xv.w * w1s[(k + 3) * HID + n];
        }
    }
    float dv = rsqrtf((float)(v + 1));
    uint4 w0, w1;
    w0.x = f2h(acc[0] * dv, acc[1] * dv);
    w0.y = f2h(acc[2] * dv, acc[3] * dv);
    w0.z = f2h(acc[4] * dv, acc[5] * dv);
    w0.w = f2h(acc[6] * dv, acc[7] * dv);
    w1.x = f2h(acc[8] * dv, acc[9] * dv);
    w1.y = f2h(acc[10] * dv, acc[11] * dv);
    w1.z = f2h(acc[12] * dv, acc[13] * dv);
    w1.w = f2h(acc[14] * dv, acc[15] * dv);
    gt[2 * (size_t)i] = w0;
    gt[2 * (size_t)i + 1] = w1;
}

// ---------------- gather conv1 (fp16 table): h1 = relu(dinv*(sum+self)+b1), fp16 out ----------------
__global__ __launch_bounds__(256) void k_gather1(const uint4* __restrict__ gt,
                                                 const int2* __restrict__ offse,
                                                 const int* __restrict__ ebuf2,
                                                 const float* __restrict__ dinv,
                                                 const float* __restrict__ b1,
                                                 uint4* __restrict__ ht, int N) {
    int i = (blockIdx.x * 256 + threadIdx.x) >> 6;
    int lane = threadIdx.x & 63;
    if (i >= N) return;
    int2 oe = offse[i];
    int j = lane & 1;
    float2 a0 = make_float2(0.f, 0.f), a1 = a0, a2 = a0, a3 = a0;
    for (int e = oe.x + (lane >> 1); e < oe.y; e += 32) {
        int s = ebuf2[e];
        uint4 v = gt[2 * (size_t)s + j];
        float2 f;
        f = h2f(v.x); a0.x += f.x; a0.y += f.y;
        f = h2f(v.y); a1.x += f.x; a1.y += f.y;
        f = h2f(v.z); a2.x += f.x; a2.y += f.y;
        f = h2f(v.w); a3.x += f.x; a3.y += f.y;
    }
#pragma unroll
    for (int mk = 2; mk <= 32; mk <<= 1) {
        a0.x += __shfl_xor(a0.x, mk); a0.y += __shfl_xor(a0.y, mk);
        a1.x += __shfl_xor(a1.x, mk); a1.y += __shfl_xor(a1.y, mk);
        a2.x += __shfl_xor(a2.x, mk); a2.y += __shfl_xor(a2.y, mk);
        a3.x += __shfl_xor(a3.x, mk); a3.y += __shfl_xor(a3.y, mk);
    }
    if (lane < 2) {
        uint4 sv = gt[2 * (size_t)i + j];
        float2 f;
        f = h2f(sv.x); a0.x += f.x; a0.y += f.y;
        f = h2f(sv.y); a1.x += f.x; a1.y += f.y;
        f = h2f(sv.z); a2.x += f.x; a2.y += f.y;
        f = h2f(sv.w); a3.x += f.x; a3.y += f.y;
        float dv = dinv[i];
        float4 bb0 = ((const float4*)b1)[2 * j];
        float4 bb1 = ((const float4*)b1)[2 * j + 1];
        float o0 = fmaxf(dv * a0.x + bb0.x, 0.f), o1 = fmaxf(dv * a0.y + bb0.y, 0.f);
        float o2 = fmaxf(dv * a1.x + bb0.z, 0.f), o3 = fmaxf(dv * a1.y + bb0.w, 0.f);
        float o4 = fmaxf(dv * a2.x + bb1.x, 0.f), o5 = fmaxf(dv * a2.y + bb1.y, 0.f);
        float o6 = fmaxf(dv * a3.x + bb1.z, 0.f), o7 = fmaxf(dv * a3.y + bb1.w, 0.f);
        uint4 w;
        w.x = f2h(o0, o1);
        w.y = f2h(o2, o3);
        w.z = f2h(o4, o5);
        w.w = f2h(o6, o7);
        ht[2 * (size_t)i + j] = w;
    }
}

// ---------------- GEMM2: g2 = (h1 @ W2) * dinv, fp16 in/out ----------------
__global__ __launch_bounds__(256) void k_gemm2(const uint4* __restrict__ ht,
                                               const float* __restrict__ W2,
                                               const float* __restrict__ dinv,
                                               uint4* __restrict__ g2t, int N) {
    __shared__ float w[HID * HID];
    w[threadIdx.x] = W2[threadIdx.x];
    __syncthreads();
    int i = blockIdx.x * 256 + threadIdx.x;
    if (i >= N) return;
    uint4 r0 = ht[2 * (size_t)i], r1 = ht[2 * (size_t)i + 1];
    float hv[HID];
    float2 f;
    f = h2f(r0.x); hv[0] = f.x; hv[1] = f.y;
    f = h2f(r0.y); hv[2] = f.x; hv[3] = f.y;
    f = h2f(r0.z); hv[4] = f.x; hv[5] = f.y;
    f = h2f(r0.w); hv[6] = f.x; hv[7] = f.y;
    f = h2f(r1.x); hv[8] = f.x; hv[9] = f.y;
    f = h2f(r1.y); hv[10] = f.x; hv[11] = f.y;
    f = h2f(r1.z); hv[12] = f.x; hv[13] = f.y;
    f = h2f(r1.w); hv[14] = f.x; hv[15] = f.y;
    float dv = dinv[i];
    float out[HID];
#pragma unroll
    for (int n = 0; n < HID; n++) out[n] = 0.f;
#pragma unroll
    for (int k = 0; k < HID; k++) {
#pragma unroll
        for (int n = 0; n < HID; n++) out[n] += hv[k] * w[k * HID + n];
    }
    uint4 w0, w1;
    w0.x = f2h(out[0] * dv, out[1] * dv);
    w0.y = f2h(out[2] * dv, out[3] * dv);
    w0.z = f2h(out[4] * dv, out[5] * dv);
    w0.w = f2h(out[6] * dv, out[7] * dv);
    w1.x = f2h(out[8] * dv, out[9] * dv);
    w1.y = f2h(out[10] * dv, out[11] * dv);
    w1.z = f2h(out[12] * dv, out[13] * dv);
    w1.w = f2h(out[14] * dv, out[15] * dv);
    g2t[2 * (size_t)i] = w0;
    g2t[2 * (size_t)i + 1] = w1;
}

// ---------------- gather conv2 (fp16 table) + fused node-dot -> nd ----------------
__global__ __launch_bounds__(256) void k_gather2(const uint4* __restrict__ g2t,
                                                 const int2* __restrict__ offse,
                                                 const int* __restrict__ ebuf2,
                                                 const float* __restrict__ dinv,
                                                 const float* __restrict__ b2,
                                                 const float* __restrict__ Wf,
                                                 const float* __restrict__ bf,
                                                 float2* __restrict__ nd, int N) {
    __shared__ float wfs[33];
    if (threadIdx.x < 33) wfs[threadIdx.x] = (threadIdx.x < 32) ? Wf[threadIdx.x] : bf[0];
    __syncthreads();
    int i = (blockIdx.x * 256 + threadIdx.x) >> 6;
    int lane = threadIdx.x & 63;
    if (i >= N) return;
    int2 oe = offse[i];
    int j = lane & 1;
    float2 a0 = make_float2(0.f, 0.f), a1 = a0, a2 = a0, a3 = a0;
    for (int e = oe.x + (lane >> 1); e < oe.y; e += 32) {
        int s = ebuf2[e];
        uint4 v = g2t[2 * (size_t)s + j];
        float2 f;
        f = h2f(v.x); a0.x += f.x; a0.y += f.y;
        f = h2f(v.y); a1.x += f.x; a1.y += f.y;
        f = h2f(v.z); a2.x += f.x; a2.y += f.y;
        f = h2f(v.w); a3.x += f.x; a3.y += f.y;
    }
#pragma unroll
    for (int mk = 2; mk <= 32; mk <<= 1) {
        a0.x += __shfl_xor(a0.x, mk); a0.y += __shfl_xor(a0.y, mk);
        a1.x += __shfl_xor(a1.x, mk); a1.y += __shfl_xor(a1.y, mk);
        a2.x += __shfl_xor(a2.x, mk); a2.y += __shfl_xor(a2.y, mk);
        a3.x += __shfl_xor(a3.x, mk); a3.y += __shfl_xor(a3.y, mk);
    }
    if (lane < 2) {
        uint4 sv = g2t[2 * (size_t)i + j];
        float2 f;
        f = h2f(sv.x); a0.x += f.x; a0.y += f.y;
        f = h2f(sv.y); a1.x += f.x; a1.y += f.y;
        f = h2f(sv.z); a2.x += f.x; a2.y += f.y;
        f = h2f(sv.w); a3.x += f.x; a3.y += f.y;
        float dv = dinv[i];
        float4 bb0 = ((const float4*)b2)[2 * j];
        float4 bb1 = ((const float4*)b2)[2 * j + 1];
        float o0 = dv * a0.x + bb0.x, o1 = dv * a0.y + bb0.y;
        float o2 = dv * a1.x + bb0.z, o3 = dv * a1.y + bb0.w;
        float o4 = dv * a2.x + bb1.x, o5 = dv * a2.y + bb1.y;
        float o6 = dv * a3.x + bb1.z, o7 = dv * a3.y + bb1.w;
        int k0 = 8 * j;
        float ps = o0 * wfs[k0 + 0] + o1 * wfs[k0 + 1] + o2 * wfs[k0 + 2] + o3 * wfs[k0 + 3] +
                   o4 * wfs[k0 + 4] + o5 * wfs[k0 + 5] + o6 * wfs[k0 + 6] + o7 * wfs[k0 + 7];
        float pd = o0 * wfs[16 + k0 + 0] + o1 * wfs[16 + k0 + 1] + o2 * wfs[16 + k0 + 2] +
                   o3 * wfs[16 + k0 + 3] + o4 * wfs[16 + k0 + 4] + o5 * wfs[16 + k0 + 5] +
                   o6 * wfs[16 + k0 + 6] + o7 * wfs[16 + k0 + 7];
        ps += __shfl_xor(ps, 1);
        pd += __shfl_xor(pd, 1);
        if (lane == 0) nd[i] = make_float2(ps, pd + wfs[32]);
    }
}

// ---------------- edge scoring: 8 B random reads from L2-resident nd ----------------
__global__ __launch_bounds__(256) void k_edge2(const int* __restrict__ src,
                                               const int* __restrict__ dst,
                                               const float2* __restrict__ nd,
                                               float* __restrict__ pred, int E) {
    int e = blockIdx.x * 256 + threadIdx.x;
    if (e >= E) return;
    pred[e] = nd[src[e]].x + nd[dst[e]].y;
}

extern "C" void kernel_launch(void* const* d_in, const int* in_sizes, int n_in,
                              void* d_out, int out_size, void* d_ws, size_t ws_size,
                              hipStream_t stream) {
    const float* x  = (const float*)d_in[0];
    const int*   ei = (const int*)d_in[1];
    const float* W1 = (const float*)d_in[2];
    const float* b1 = (const float*)d_in[3];
    const float* W2 = (const float*)d_in[4];
    const float* b2 = (const float*)d_in[5];
    const float* Wf = (const float*)d_in[6];
    const float* bf = (const float*)d_in[7];
    float* pred = (float*)d_out;

    const int N = N_NODES, E = N_EDGES;
    const int* src = ei;
    const int* dst = ei + E;

    // workspace layout (bytes); g2t aliases ebuf (dead after k_sort2). Total ~38 MB.
    char* w = (char*)d_ws;
    int*      cursor = (int*)(w + 0x0);           // 25 KB (stride CPAD)
    float*    dinv   = (float*)(w + 0x10000);     // 400 KB
    int2*     offse  = (int2*)(w + 0x80000);      // 800 KB
    float2*   nd     = (float2*)(w + 0x150000);   // 800 KB
    unsigned* ebuf   = (unsigned*)(w + 0x220000); // 391*9216*4 = 14.42 MB (dead after sort2)
    uint4*    g2t    = (uint4*)(w + 0x220000);    // 3.2 MB (aliases ebuf)
    int*      ebuf2  = (int*)(w + 0x1000000);     // 14.42 MB
    uint4*    gt     = (uint4*)(w + 0x1E00000);   // 3.2 MB (fp16 g table)
    uint4*    ht     = (uint4*)(w + 0x2140000);   // 3.2 MB (fp16 h1) -> end ~0x2450000

    const int B = 256;
    int gE   = (E + B - 1) / B;  // 12500
    int gN   = (N + B - 1) / B;  // 391
    int gN64 = (N * 64) / B;     // 25000 (wave per node)

    hipMemsetAsync(cursor, 0, NB * CPAD * sizeof(int), stream);
    k_part<<<NCHUNK, B, 0, stream>>>(src, dst, cursor, ebuf, E);
    k_sort2<<<NB, B, 0, stream>>>(ebuf, cursor, x, W1, ebuf2, offse, dinv, gt, N);
    k_gather1<<<gN64, B, 0, stream>>>(gt, offse, ebuf2, dinv, b1, ht, N);
    k_gemm2<<<gN, B, 0, stream>>>(ht, W2, dinv, g2t, N);
    k_gather2<<<gN64, B, 0, stream>>>(g2t, offse, ebuf2, dinv, b2, Wf, bf, nd, N);
    k_edge2<<<gE, B, 0, stream>>>(src, dst, nd, pred, E);
}

// Round 11
// 194.373 us; speedup vs baseline: 1.3725x; 1.1396x over previous
//
#include <hip/hip_runtime.h>
#include <hip/hip_fp16.h>

#define N_NODES 100000
#define N_EDGES 3200000
#define F_IN 128
#define HID 16

#define SHIFT 8
#define NPB 256                                 // nodes per bucket
#define NB 391                                  // ceil(N/256)
#define CHUNK 4096
#define NCHUNK ((N_EDGES + CHUNK - 1) / CHUNK)  // 782
#define MAXBE 9216                              // region cap per bucket (mean 8184, +11 sigma)
#define SMAX 36                                 // MAXBE/256
#define CPAD 16

__device__ __forceinline__ float2 h2f(unsigned u) {
    __half2 h;
    *reinterpret_cast<unsigned*>(&h) = u;
    return __half22float2(h);
}
__device__ __forceinline__ unsigned f2h(float a, float b) {
    __half2 h = __floats2half2_rn(a, b);
    return *reinterpret_cast<unsigned*>(&h);
}

// ---------------- partition into 391 fixed bucket regions, LDS-staged coalesced writes ----------------
__global__ __launch_bounds__(256) void k_part(const int* __restrict__ src,
                                              const int* __restrict__ dst,
                                              int* __restrict__ cursor,
                                              unsigned* __restrict__ ebuf, int E) {
    __shared__ int lcnt[512];
    __shared__ int sc[512];
    __shared__ int lcur[512];
    __shared__ int dlt[512];
    __shared__ unsigned sbuf[CHUNK];         // 16 KB
    __shared__ unsigned short sbkt[CHUNK];   // 8 KB
    int t = threadIdx.x;
    lcnt[t] = 0;
    lcnt[t + 256] = 0;
    __syncthreads();
    int e0 = blockIdx.x * CHUNK;
    int ne = min(CHUNK, E - e0);
    for (int e = t; e < ne; e += 256) atomicAdd(&lcnt[dst[e0 + e] >> SHIFT], 1);
    __syncthreads();
    sc[t] = lcnt[t];
    sc[t + 256] = lcnt[t + 256];
    __syncthreads();
#pragma unroll
    for (int o = 1; o < 256; o <<= 1) {
        int xv = (t >= o) ? sc[t - o] : 0;
        int yv = (t >= o) ? sc[256 + t - o] : 0;
        __syncthreads();
        sc[t] += xv;
        sc[256 + t] += yv;
        __syncthreads();
    }
    int tot1 = sc[255];
    __syncthreads();
    sc[256 + t] += tot1;
    __syncthreads();
    {
        int b1 = t, b2 = t + 256;
        int c1 = lcnt[b1], c2 = lcnt[b2];
        int o1 = sc[b1] - c1, o2 = sc[b2] - c2;
        lcur[b1] = o1;
        lcur[b2] = o2;
        if (b1 < NB && c1) dlt[b1] = b1 * MAXBE + atomicAdd(&cursor[b1 * CPAD], c1) - o1;
        if (b2 < NB && c2) dlt[b2] = b2 * MAXBE + atomicAdd(&cursor[b2 * CPAD], c2) - o2;
    }
    __syncthreads();
    for (int e = t; e < ne; e += 256) {
        int d = dst[e0 + e];
        int b = d >> SHIFT;
        int p = atomicAdd(&lcur[b], 1);
        sbuf[p] = ((unsigned)src[e0 + e] << SHIFT) | (unsigned)(d & (NPB - 1));
        sbkt[p] = (unsigned short)b;
    }
    __syncthreads();
    for (int k = t; k < ne; k += 256) ebuf[k + dlt[sbkt[k]]] = sbuf[k];
}

// ---------------- per-bucket counting-sort (single reg-cached read) + fused GEMM1 (fp16 out) ----------------
__global__ __launch_bounds__(256) void k_sort2(const unsigned* __restrict__ ebuf,
                                               const int* __restrict__ cursor,
                                               const float* __restrict__ x,
                                               const float* __restrict__ W1,
                                               int* __restrict__ ebuf2,
                                               int2* __restrict__ offse,
                                               float* __restrict__ dinv,
                                               uint4* __restrict__ gt, int N) {
    __shared__ int hist[NPB];
    __shared__ int sc2[NPB];
    __shared__ int cur[NPB];
    __shared__ int sbufS[MAXBE];      // 36 KB
    __shared__ float w1s[F_IN * HID]; // 8 KB
    int t = threadIdx.x;
    int b = blockIdx.x;
    for (int idx = t; idx < F_IN * HID; idx += 256) w1s[idx] = W1[idx];
    hist[t] = 0;
    __syncthreads();
    int cnt = min(cursor[b * CPAD], MAXBE);
    int base = b * MAXBE;
    unsigned eu[SMAX];
    int nq = 0;
    for (int e = t; e < cnt; e += 256) eu[nq++] = ebuf[base + e];
    for (int q = 0; q < nq; q++) atomicAdd(&hist[eu[q] & (NPB - 1u)], 1);
    __syncthreads();
    int v = hist[t];
    sc2[t] = v;
    __syncthreads();
#pragma unroll
    for (int o = 1; o < NPB; o <<= 1) {
        int xv = (t >= o) ? sc2[t - o] : 0;
        __syncthreads();
        sc2[t] += xv;
        __syncthreads();
    }
    int ex = sc2[t] - v;
    cur[t] = ex;
    int i = b * NPB + t;
    if (i < N) {
        offse[i] = make_int2(base + ex, base + ex + v);
        dinv[i] = rsqrtf((float)(v + 1));  // +1 self-loop
    }
    __syncthreads();
    for (int q = 0; q < nq; q++) {
        int p = atomicAdd(&cur[eu[q] & (NPB - 1u)], 1);
        sbufS[p] = (int)(eu[q] >> SHIFT);
    }
    __syncthreads();
    for (int k = t; k < cnt; k += 256) ebuf2[base + k] = sbufS[k];  // coalesced
    // ---- fused GEMM1: g = (x @ W1) * dinv, fp16 storage (1 thread/row, 256 nodes) ----
    if (i >= N) return;
    float acc[HID];
#pragma unroll
    for (int n = 0; n < HID; n++) acc[n] = 0.f;
    const float4* xr = (const float4*)(x + (size_t)i * F_IN);
#pragma unroll 4
    for (int k4 = 0; k4 < F_IN / 4; k4++) {
        float4 xv = xr[k4];
        int k = k4 * 4;
#pragma unroll
        for (int n = 0; n < HID; n++) {
            acc[n] += xv.x * w1s[(k + 0) * HID + n] + xv.y * w1s[(k + 1) * HID + n] +
                      xv.z * w1s[(k + 2) * HID + n] + xv.w * w1s[(k + 3) * HID + n];
        }
    }
    float dv = rsqrtf((float)(v + 1));
    uint4 w0, w1;
    w0.x = f2h(acc[0] * dv, acc[1] * dv);
    w0.y = f2h(acc[2] * dv, acc[3] * dv);
    w0.z = f2h(acc[4] * dv, acc[5] * dv);
    w0.w = f2h(acc[6] * dv, acc[7] * dv);
    w1.x = f2h(acc[8] * dv, acc[9] * dv);
    w1.y = f2h(acc[10] * dv, acc[11] * dv);
    w1.z = f2h(acc[12] * dv, acc[13] * dv);
    w1.w = f2h(acc[14] * dv, acc[15] * dv);
    gt[2 * (size_t)i] = w0;
    gt[2 * (size_t)i + 1] = w1;
}

// ---------------- gather conv1, slice-parallel: lane = (edge_slot<<3)|slice ----------------
// wave per node; 8 edges in flight x 8 component-slices (half2 each); 3-stage tree.
__global__ __launch_bounds__(256) void k_gather1(const unsigned* __restrict__ gtu,
                                                 const int2* __restrict__ offse,
                                                 const int* __restrict__ ebuf2,
                                                 const float* __restrict__ dinv,
                                                 const float* __restrict__ b1,
                                                 unsigned* __restrict__ htu, int N) {
    int i = (blockIdx.x * 256 + threadIdx.x) >> 6;  // node = global wave id
    int lane = threadIdx.x & 63;
    if (i >= N) return;
    int eo = lane >> 3, s = lane & 7;
    int2 oe = offse[i];
    float2 a = make_float2(0.f, 0.f);
    for (int e = oe.x + eo; e < oe.y; e += 8) {
        int sv = ebuf2[e];
        float2 f = h2f(gtu[sv * 8 + s]);
        a.x += f.x;
        a.y += f.y;
    }
    a.x += __shfl_xor(a.x, 8);  a.y += __shfl_xor(a.y, 8);
    a.x += __shfl_xor(a.x, 16); a.y += __shfl_xor(a.y, 16);
    a.x += __shfl_xor(a.x, 32); a.y += __shfl_xor(a.y, 32);
    if (eo == 0) {
        float2 f = h2f(gtu[i * 8 + s]);  // self-loop
        a.x += f.x;
        a.y += f.y;
        float dv = dinv[i];
        float2 bb = ((const float2*)b1)[s];
        float o0 = fmaxf(dv * a.x + bb.x, 0.f);
        float o1 = fmaxf(dv * a.y + bb.y, 0.f);
        htu[i * 8 + s] = f2h(o0, o1);
    }
}

// ---------------- GEMM2 + node-dot fold: q[i] = dv * ((h1@W2) . wf_lo, (h1@W2) . wf_hi) ----------------
__global__ __launch_bounds__(256) void k_gemm2q(const uint4* __restrict__ ht,
                                                const float* __restrict__ W2,
                                                const float* __restrict__ dinv,
                                                const float* __restrict__ Wf,
                                                float2* __restrict__ q, int N) {
    __shared__ float w[HID * HID];
    __shared__ float wfs[32];
    w[threadIdx.x] = W2[threadIdx.x];
    if (threadIdx.x < 32) wfs[threadIdx.x] = Wf[threadIdx.x];
    __syncthreads();
    int i = blockIdx.x * 256 + threadIdx.x;
    if (i >= N) return;
    uint4 r0 = ht[2 * (size_t)i], r1 = ht[2 * (size_t)i + 1];
    float hv[HID];
    float2 f;
    f = h2f(r0.x); hv[0] = f.x; hv[1] = f.y;
    f = h2f(r0.y); hv[2] = f.x; hv[3] = f.y;
    f = h2f(r0.z); hv[4] = f.x; hv[5] = f.y;
    f = h2f(r0.w); hv[6] = f.x; hv[7] = f.y;
    f = h2f(r1.x); hv[8] = f.x; hv[9] = f.y;
    f = h2f(r1.y); hv[10] = f.x; hv[11] = f.y;
    f = h2f(r1.z); hv[12] = f.x; hv[13] = f.y;
    f = h2f(r1.w); hv[14] = f.x; hv[15] = f.y;
    float out[HID];
#pragma unroll
    for (int n = 0; n < HID; n++) out[n] = 0.f;
#pragma unroll
    for (int k = 0; k < HID; k++) {
#pragma unroll
        for (int n = 0; n < HID; n++) out[n] += hv[k] * w[k * HID + n];
    }
    float qs = 0.f, qd = 0.f;
#pragma unroll
    for (int n = 0; n < HID; n++) {
        qs += out[n] * wfs[n];
        qd += out[n] * wfs[16 + n];
    }
    float dv = dinv[i];
    q[i] = make_float2(qs * dv, qd * dv);
}

// ---------------- gather conv2 on scalars: nd[i] = dv*(sum q + q[i]) + C ----------------
// 16 lanes per node, 4 nodes per wave; q table 800 KB (L2-resident).
__global__ __launch_bounds__(256) void k_gather2(const float2* __restrict__ q,
                                                 const int2* __restrict__ offse,
                                                 const int* __restrict__ ebuf2,
                                                 const float* __restrict__ dinv,
                                                 const float* __restrict__ b2,
                                                 const float* __restrict__ Wf,
                                                 const float* __restrict__ bf,
                                                 float2* __restrict__ nd, int N) {
    __shared__ float2 C;
    if (threadIdx.x == 0) {
        float c1 = 0.f, c2 = 0.f;
#pragma unroll
        for (int k = 0; k < HID; k++) {
            c1 += b2[k] * Wf[k];
            c2 += b2[k] * Wf[16 + k];
        }
        C = make_float2(c1, c2 + bf[0]);
    }
    __syncthreads();
    int grp = threadIdx.x >> 4, l = threadIdx.x & 15;
    int i = blockIdx.x * 16 + grp;
    if (i >= N) return;
    int2 oe = offse[i];
    float2 a = make_float2(0.f, 0.f);
    for (int e = oe.x + l; e < oe.y; e += 16) {
        float2 qq = q[ebuf2[e]];
        a.x += qq.x;
        a.y += qq.y;
    }
    a.x += __shfl_xor(a.x, 1); a.y += __shfl_xor(a.y, 1);
    a.x += __shfl_xor(a.x, 2); a.y += __shfl_xor(a.y, 2);
    a.x += __shfl_xor(a.x, 4); a.y += __shfl_xor(a.y, 4);
    a.x += __shfl_xor(a.x, 8); a.y += __shfl_xor(a.y, 8);
    if (l == 0) {
        float2 self = q[i];
        float dv = dinv[i];
        nd[i] = make_float2(dv * (a.x + self.x) + C.x, dv * (a.y + self.y) + C.y);
    }
}

// ---------------- edge scoring: 8 B random reads from L2-resident nd ----------------
__global__ __launch_bounds__(256) void k_edge2(const int* __restrict__ src,
                                               const int* __restrict__ dst,
                                               const float2* __restrict__ nd,
                                               float* __restrict__ pred, int E) {
    int e = blockIdx.x * 256 + threadIdx.x;
    if (e >= E) return;
    pred[e] = nd[src[e]].x + nd[dst[e]].y;
}

extern "C" void kernel_launch(void* const* d_in, const int* in_sizes, int n_in,
                              void* d_out, int out_size, void* d_ws, size_t ws_size,
                              hipStream_t stream) {
    const float* x  = (const float*)d_in[0];
    const int*   ei = (const int*)d_in[1];
    const float* W1 = (const float*)d_in[2];
    const float* b1 = (const float*)d_in[3];
    const float* W2 = (const float*)d_in[4];
    const float* b2 = (const float*)d_in[5];
    const float* Wf = (const float*)d_in[6];
    const float* bf = (const float*)d_in[7];
    float* pred = (float*)d_out;

    const int N = N_NODES, E = N_EDGES;
    const int* src = ei;
    const int* dst = ei + E;

    // workspace layout (bytes); q aliases ebuf (dead after k_sort2). Total ~38 MB.
    char* w = (char*)d_ws;
    int*      cursor = (int*)(w + 0x0);           // 25 KB (stride CPAD)
    float*    dinv   = (float*)(w + 0x10000);     // 400 KB
    int2*     offse  = (int2*)(w + 0x80000);      // 800 KB
    float2*   nd     = (float2*)(w + 0x150000);   // 800 KB
    unsigned* ebuf   = (unsigned*)(w + 0x220000); // 391*9216*4 = 14.42 MB (dead after sort2)
    float2*   q      = (float2*)(w + 0x220000);   // 800 KB (aliases ebuf)
    int*      ebuf2  = (int*)(w + 0x1000000);     // 14.42 MB
    uint4*    gt     = (uint4*)(w + 0x1E00000);   // 3.2 MB (fp16 g table)
    uint4*    ht     = (uint4*)(w + 0x2140000);   // 3.2 MB (fp16 h1) -> end ~0x2450000

    const int B = 256;
    int gE   = (E + B - 1) / B;   // 12500
    int gN   = (N + B - 1) / B;   // 391
    int gN64 = (N * 64) / B;      // 25000 (wave per node)
    int gN16 = (N + 15) / 16;     // 6250 (16 lanes per node)

    hipMemsetAsync(cursor, 0, NB * CPAD * sizeof(int), stream);
    k_part<<<NCHUNK, B, 0, stream>>>(src, dst, cursor, ebuf, E);
    k_sort2<<<NB, B, 0, stream>>>(ebuf, cursor, x, W1, ebuf2, offse, dinv, gt, N);
    k_gather1<<<gN64, B, 0, stream>>>((const unsigned*)gt, offse, ebuf2, dinv, b1,
                                      (unsigned*)ht, N);
    k_gemm2q<<<gN, B, 0, stream>>>(ht, W2, dinv, Wf, q, N);
    k_gather2<<<gN16, B, 0, stream>>>(q, offse, ebuf2, dinv, b2, Wf, bf, nd, N);
    k_edge2<<<gE, B, 0, stream>>>(src, dst, nd, pred, E);
}

// Round 12
// 181.271 us; speedup vs baseline: 1.4717x; 1.0723x over previous
//
#include <hip/hip_runtime.h>
#include <hip/hip_fp16.h>

#define N_NODES 100000
#define N_EDGES 3200000
#define F_IN 128
#define HID 16

#define SHIFT 8
#define NPB 256                                 // nodes per bucket
#define NB 391                                  // ceil(N/256)
#define CHUNK 4096
#define NCHUNK ((N_EDGES + CHUNK - 1) / CHUNK)  // 782
#define MAXBE 9216                              // region cap per bucket (mean 8184, +11 sigma)
#define SMAX 18                                 // MAXBE/512
#define CPAD 16

__device__ __forceinline__ float2 h2f(unsigned u) {
    __half2 h;
    *reinterpret_cast<unsigned*>(&h) = u;
    return __half22float2(h);
}
__device__ __forceinline__ unsigned f2h(float a, float b) {
    __half2 h = __floats2half2_rn(a, b);
    return *reinterpret_cast<unsigned*>(&h);
}

// ---------------- partition into 391 fixed bucket regions, 512 threads, LDS-staged writes ----------------
__global__ __launch_bounds__(512) void k_part(const int* __restrict__ src,
                                              const int* __restrict__ dst,
                                              int* __restrict__ cursor,
                                              unsigned* __restrict__ ebuf, int E) {
    __shared__ int lcnt[512];
    __shared__ int sc[512];
    __shared__ int lcur[512];
    __shared__ int dlt[512];
    __shared__ unsigned sbuf[CHUNK];         // 16 KB
    __shared__ unsigned short sbkt[CHUNK];   // 8 KB
    int t = threadIdx.x;
    lcnt[t] = 0;
    __syncthreads();
    int e0 = blockIdx.x * CHUNK;
    int ne = min(CHUNK, E - e0);
    for (int e = t; e < ne; e += 512) atomicAdd(&lcnt[dst[e0 + e] >> SHIFT], 1);
    __syncthreads();
    sc[t] = lcnt[t];
    __syncthreads();
#pragma unroll
    for (int o = 1; o < 512; o <<= 1) {
        int xv = (t >= o) ? sc[t - o] : 0;
        __syncthreads();
        sc[t] += xv;
        __syncthreads();
    }
    {
        int c = lcnt[t];
        int o = sc[t] - c;
        lcur[t] = o;
        if (t < NB && c) dlt[t] = t * MAXBE + atomicAdd(&cursor[t * CPAD], c) - o;
    }
    __syncthreads();
    for (int e = t; e < ne; e += 512) {
        int d = dst[e0 + e];
        int b = d >> SHIFT;
        int p = atomicAdd(&lcur[b], 1);
        sbuf[p] = ((unsigned)src[e0 + e] << SHIFT) | (unsigned)(d & (NPB - 1));
        sbkt[p] = (unsigned short)b;
    }
    __syncthreads();
    for (int k = t; k < ne; k += 512) ebuf[k + dlt[sbkt[k]]] = sbuf[k];
}

// ---------------- per-bucket counting-sort (512 thr, single reg-cached read) + fused GEMM1 ----------------
__global__ __launch_bounds__(512) void k_sort2(const unsigned* __restrict__ ebuf,
                                               const int* __restrict__ cursor,
                                               const float* __restrict__ x,
                                               const float* __restrict__ W1,
                                               int* __restrict__ ebuf2,
                                               int2* __restrict__ offse,
                                               float* __restrict__ dinv,
                                               uint4* __restrict__ gt, int N) {
    __shared__ int hist[NPB];
    __shared__ int sc2[NPB];
    __shared__ int cur[NPB];
    __shared__ int sbufS[MAXBE];      // 36 KB
    __shared__ float w1s[F_IN * HID]; // 8 KB
    int t = threadIdx.x;
    int b = blockIdx.x;
    for (int idx = t; idx < F_IN * HID; idx += 512) w1s[idx] = W1[idx];
    if (t < NPB) hist[t] = 0;
    __syncthreads();
    int cnt = min(cursor[b * CPAD], MAXBE);
    int base = b * MAXBE;
    unsigned eu[SMAX];
    int nq = 0;
    for (int e = t; e < cnt; e += 512) eu[nq++] = ebuf[base + e];
    for (int q = 0; q < nq; q++) atomicAdd(&hist[eu[q] & (NPB - 1u)], 1);
    __syncthreads();
    int v = (t < NPB) ? hist[t] : 0;
    if (t < NPB) sc2[t] = v;
    __syncthreads();
#pragma unroll
    for (int o = 1; o < NPB; o <<= 1) {
        int xv = (t < NPB && t >= o) ? sc2[t - o] : 0;
        __syncthreads();
        if (t < NPB) sc2[t] += xv;
        __syncthreads();
    }
    if (t < NPB) {
        int ex = sc2[t] - v;
        cur[t] = ex;
        int i = b * NPB + t;
        if (i < N) {
            offse[i] = make_int2(base + ex, base + ex + v);
            dinv[i] = rsqrtf((float)(v + 1));  // +1 self-loop
        }
    }
    __syncthreads();
    for (int q = 0; q < nq; q++) {
        int p = atomicAdd(&cur[eu[q] & (NPB - 1u)], 1);
        sbufS[p] = (int)(eu[q] >> SHIFT);
    }
    __syncthreads();
    for (int k = t; k < cnt; k += 512) ebuf2[base + k] = sbufS[k];  // coalesced
    // ---- fused GEMM1: g = (x @ W1) * dinv, fp16 storage (2 lanes/row, 256 nodes) ----
    int r = t >> 1, hf = t & 1;
    int i = b * NPB + r;
    float acc[HID];
#pragma unroll
    for (int n = 0; n < HID; n++) acc[n] = 0.f;
    if (i < N) {
        const float4* xr = (const float4*)(x + (size_t)i * F_IN + hf * (F_IN / 2));
#pragma unroll 4
        for (int k4 = 0; k4 < F_IN / 8; k4++) {
            float4 xv = xr[k4];
            int k = hf * (F_IN / 2) + k4 * 4;
#pragma unroll
            for (int n = 0; n < HID; n++) {
                acc[n] += xv.x * w1s[(k + 0) * HID + n] + xv.y * w1s[(k + 1) * HID + n] +
                          xv.z * w1s[(k + 2) * HID + n] + xv.w * w1s[(k + 3) * HID + n];
            }
        }
    }
#pragma unroll
    for (int n = 0; n < HID; n++) acc[n] += __shfl_xor(acc[n], 1);
    if (hf == 0 && i < N) {
        float dv = rsqrtf((float)(hist[r] + 1));
        uint4 w0, w1;
        w0.x = f2h(acc[0] * dv, acc[1] * dv);
        w0.y = f2h(acc[2] * dv, acc[3] * dv);
        w0.z = f2h(acc[4] * dv, acc[5] * dv);
        w0.w = f2h(acc[6] * dv, acc[7] * dv);
        w1.x = f2h(acc[8] * dv, acc[9] * dv);
        w1.y = f2h(acc[10] * dv, acc[11] * dv);
        w1.z = f2h(acc[12] * dv, acc[13] * dv);
        w1.w = f2h(acc[14] * dv, acc[15] * dv);
        gt[2 * (size_t)i] = w0;
        gt[2 * (size_t)i + 1] = w1;
    }
}

// ---------------- gather conv1, slice-parallel: lane = (edge_slot<<3)|slice ----------------
__global__ __launch_bounds__(256) void k_gather1(const unsigned* __restrict__ gtu,
                                                 const int2* __restrict__ offse,
                                                 const int* __restrict__ ebuf2,
                                                 const float* __restrict__ dinv,
                                                 const float* __restrict__ b1,
                                                 unsigned* __restrict__ htu, int N) {
    int i = (blockIdx.x * 256 + threadIdx.x) >> 6;  // node = global wave id
    int lane = threadIdx.x & 63;
    if (i >= N) return;
    int eo = lane >> 3, s = lane & 7;
    int2 oe = offse[i];
    float2 a = make_float2(0.f, 0.f);
    for (int e = oe.x + eo; e < oe.y; e += 8) {
        int sv = ebuf2[e];
        float2 f = h2f(gtu[sv * 8 + s]);
        a.x += f.x;
        a.y += f.y;
    }
    a.x += __shfl_xor(a.x, 8);  a.y += __shfl_xor(a.y, 8);
    a.x += __shfl_xor(a.x, 16); a.y += __shfl_xor(a.y, 16);
    a.x += __shfl_xor(a.x, 32); a.y += __shfl_xor(a.y, 32);
    if (eo == 0) {
        float2 f = h2f(gtu[i * 8 + s]);  // self-loop
        a.x += f.x;
        a.y += f.y;
        float dv = dinv[i];
        float2 bb = ((const float2*)b1)[s];
        float o0 = fmaxf(dv * a.x + bb.x, 0.f);
        float o1 = fmaxf(dv * a.y + bb.y, 0.f);
        htu[i * 8 + s] = f2h(o0, o1);
    }
}

// ---------------- GEMM2 + node-dot fold: q[i] = dv * ((h1@W2) . wf_lo, (h1@W2) . wf_hi) ----------------
__global__ __launch_bounds__(256) void k_gemm2q(const uint4* __restrict__ ht,
                                                const float* __restrict__ W2,
                                                const float* __restrict__ dinv,
                                                const float* __restrict__ Wf,
                                                float2* __restrict__ q, int N) {
    __shared__ float w[HID * HID];
    __shared__ float wfs[32];
    w[threadIdx.x] = W2[threadIdx.x];
    if (threadIdx.x < 32) wfs[threadIdx.x] = Wf[threadIdx.x];
    __syncthreads();
    int i = blockIdx.x * 256 + threadIdx.x;
    if (i >= N) return;
    uint4 r0 = ht[2 * (size_t)i], r1 = ht[2 * (size_t)i + 1];
    float hv[HID];
    float2 f;
    f = h2f(r0.x); hv[0] = f.x; hv[1] = f.y;
    f = h2f(r0.y); hv[2] = f.x; hv[3] = f.y;
    f = h2f(r0.z); hv[4] = f.x; hv[5] = f.y;
    f = h2f(r0.w); hv[6] = f.x; hv[7] = f.y;
    f = h2f(r1.x); hv[8] = f.x; hv[9] = f.y;
    f = h2f(r1.y); hv[10] = f.x; hv[11] = f.y;
    f = h2f(r1.z); hv[12] = f.x; hv[13] = f.y;
    f = h2f(r1.w); hv[14] = f.x; hv[15] = f.y;
    float out[HID];
#pragma unroll
    for (int n = 0; n < HID; n++) out[n] = 0.f;
#pragma unroll
    for (int k = 0; k < HID; k++) {
#pragma unroll
        for (int n = 0; n < HID; n++) out[n] += hv[k] * w[k * HID + n];
    }
    float qs = 0.f, qd = 0.f;
#pragma unroll
    for (int n = 0; n < HID; n++) {
        qs += out[n] * wfs[n];
        qd += out[n] * wfs[16 + n];
    }
    float dv = dinv[i];
    q[i] = make_float2(qs * dv, qd * dv);
}

// ---------------- gather conv2 on scalars: nd[i] = dv*(sum q + q[i]) + C ----------------
__global__ __launch_bounds__(256) void k_gather2(const float2* __restrict__ q,
                                                 const int2* __restrict__ offse,
                                                 const int* __restrict__ ebuf2,
                                                 const float* __restrict__ dinv,
                                                 const float* __restrict__ b2,
                                                 const float* __restrict__ Wf,
                                                 const float* __restrict__ bf,
                                                 float2* __restrict__ nd, int N) {
    __shared__ float2 C;
    if (threadIdx.x == 0) {
        float c1 = 0.f, c2 = 0.f;
#pragma unroll
        for (int k = 0; k < HID; k++) {
            c1 += b2[k] * Wf[k];
            c2 += b2[k] * Wf[16 + k];
        }
        C = make_float2(c1, c2 + bf[0]);
    }
    __syncthreads();
    int grp = threadIdx.x >> 4, l = threadIdx.x & 15;
    int i = blockIdx.x * 16 + grp;
    if (i >= N) return;
    int2 oe = offse[i];
    float2 a = make_float2(0.f, 0.f);
    for (int e = oe.x + l; e < oe.y; e += 16) {
        float2 qq = q[ebuf2[e]];
        a.x += qq.x;
        a.y += qq.y;
    }
    a.x += __shfl_xor(a.x, 1); a.y += __shfl_xor(a.y, 1);
    a.x += __shfl_xor(a.x, 2); a.y += __shfl_xor(a.y, 2);
    a.x += __shfl_xor(a.x, 4); a.y += __shfl_xor(a.y, 4);
    a.x += __shfl_xor(a.x, 8); a.y += __shfl_xor(a.y, 8);
    if (l == 0) {
        float2 self = q[i];
        float dv = dinv[i];
        nd[i] = make_float2(dv * (a.x + self.x) + C.x, dv * (a.y + self.y) + C.y);
    }
}

// ---------------- edge scoring: 8 B random reads from L2-resident nd ----------------
__global__ __launch_bounds__(256) void k_edge2(const int* __restrict__ src,
                                               const int* __restrict__ dst,
                                               const float2* __restrict__ nd,
                                               float* __restrict__ pred, int E) {
    int e = blockIdx.x * 256 + threadIdx.x;
    if (e >= E) return;
    pred[e] = nd[src[e]].x + nd[dst[e]].y;
}

extern "C" void kernel_launch(void* const* d_in, const int* in_sizes, int n_in,
                              void* d_out, int out_size, void* d_ws, size_t ws_size,
                              hipStream_t stream) {
    const float* x  = (const float*)d_in[0];
    const int*   ei = (const int*)d_in[1];
    const float* W1 = (const float*)d_in[2];
    const float* b1 = (const float*)d_in[3];
    const float* W2 = (const float*)d_in[4];
    const float* b2 = (const float*)d_in[5];
    const float* Wf = (const float*)d_in[6];
    const float* bf = (const float*)d_in[7];
    float* pred = (float*)d_out;

    const int N = N_NODES, E = N_EDGES;
    const int* src = ei;
    const int* dst = ei + E;

    // workspace layout (bytes); q aliases ebuf (dead after k_sort2). Total ~38 MB.
    char* w = (char*)d_ws;
    int*      cursor = (int*)(w + 0x0);           // 25 KB (stride CPAD)
    float*    dinv   = (float*)(w + 0x10000);     // 400 KB
    int2*     offse  = (int2*)(w + 0x80000);      // 800 KB
    float2*   nd     = (float2*)(w + 0x150000);   // 800 KB
    unsigned* ebuf   = (unsigned*)(w + 0x220000); // 391*9216*4 = 14.42 MB (dead after sort2)
    float2*   q      = (float2*)(w + 0x220000);   // 800 KB (aliases ebuf)
    int*      ebuf2  = (int*)(w + 0x1000000);     // 14.42 MB
    uint4*    gt     = (uint4*)(w + 0x1E00000);   // 3.2 MB (fp16 g table)
    uint4*    ht     = (uint4*)(w + 0x2140000);   // 3.2 MB (fp16 h1) -> end ~0x2450000

    const int B = 256;
    int gE   = (E + B - 1) / B;   // 12500
    int gN   = (N + B - 1) / B;   // 391
    int gN64 = (N * 64) / B;      // 25000 (wave per node)
    int gN16 = (N + 15) / 16;     // 6250 (16 lanes per node)

    hipMemsetAsync(cursor, 0, NB * CPAD * sizeof(int), stream);
    k_part<<<NCHUNK, 512, 0, stream>>>(src, dst, cursor, ebuf, E);
    k_sort2<<<NB, 512, 0, stream>>>(ebuf, cursor, x, W1, ebuf2, offse, dinv, gt, N);
    k_gather1<<<gN64, B, 0, stream>>>((const unsigned*)gt, offse, ebuf2, dinv, b1,
                                      (unsigned*)ht, N);
    k_gemm2q<<<gN, B, 0, stream>>>(ht, W2, dinv, Wf, q, N);
    k_gather2<<<gN16, B, 0, stream>>>(q, offse, ebuf2, dinv, b2, Wf, bf, nd, N);
    k_edge2<<<gE, B, 0, stream>>>(src, dst, nd, pred, E);
}